// Round 5
// baseline (11643.134 us; speedup 1.0000x reference)
//
#include <hip/hip_runtime.h>
#include <math.h>

// Model: 10 parallel LSTMs -> MI-LSTM w/ stream attention -> linear head.
// All f32 (no fp32-input MFMA on CDNA4; accuracy threshold requires f32).
//
#define SS 10
#define TT 256
#define BB 128
#define HH 128
#define II 128
#define G4 512     // 4H
#define ZK 256     // I + H (fused [x|h] contraction)
#define NCOL 2944  // phase-D fused weight columns: Ui(1280)|Uc(1280)|Uf(128)|Uo(128)|Wa(128)
#define NBLK 92    // cooperative blocks: 92 x 32 cols = 2944

#define SZ_W2T   (SS*ZK*G4)        // 1,310,720
#define SZ_BIAS2 (SS*G4)           // 5,120
#define SZ_UBIG  (HH*NCOL)         // 376,832
#define SZ_TILDE (SS*TT*BB*HH)     // 41,943,040
#define SZ_X     (TT*SS*BB*HH)     // 41,943,040
#define SZ_XFO   (TT*BB*HH)        // 4,194,304

#define OFF_W2T   0
#define OFF_BIAS2 (OFF_W2T + SZ_W2T)
#define OFF_UBIG  (OFF_BIAS2 + SZ_BIAS2)
#define OFF_TILDE (OFF_UBIG + SZ_UBIG)
#define OFF_XI    (OFF_TILDE + SZ_TILDE)
#define OFF_XC    (OFF_XI + SZ_X)
#define OFF_XF    (OFF_XC + SZ_X)
#define OFF_XO    (OFF_XF + SZ_XFO)
#define OFF_HT    (OFF_XO + SZ_XFO)
#define OFF_CT    (OFF_HT + BB*HH)
#define OFF_ACT   (OFF_CT + BB*HH)
#define OFF_CNT   (OFF_ACT + BB*NCOL)

__device__ __forceinline__ float sigf(float x){ return 1.0f/(1.0f+expf(-x)); }

// coherent-per-access helpers (sc0 sc1 path; no cache-wide wb/inv)
__device__ __forceinline__ float ald(const float* p){
  return __hip_atomic_load(p, __ATOMIC_RELAXED, __HIP_MEMORY_SCOPE_AGENT);
}
__device__ __forceinline__ void ast(float* p, float v){
  __hip_atomic_store(p, v, __ATOMIC_RELAXED, __HIP_MEMORY_SCOPE_AGENT);
}

// ---------------- prep: fused transposed LSTM weights (b128-friendly) ----------------
// w4t layout: [s][kk4(64)][j(512)][q(4)] with value = fusedW[kk4*4+q][j]
__global__ __launch_bounds__(256) void prep_w2t(const float* __restrict__ Wih, const float* __restrict__ Whh,
                                                const float* __restrict__ bih, const float* __restrict__ bhh,
                                                float* __restrict__ w2t, float* __restrict__ bias2){
  int idx = blockIdx.x*256 + threadIdx.x;
  if (idx < SZ_W2T){
    int q = idx & 3; int j = (idx >> 2) & 511; int kk4 = (idx >> 11) & 63; int s = idx >> 17;
    int kk = kk4*4 + q;
    float v = (kk < II) ? Wih[(s*G4 + j)*II + kk] : Whh[(s*G4 + j)*HH + (kk - II)];
    w2t[idx] = v;
  }
  if (idx < SZ_BIAS2) bias2[idx] = bih[idx] + bhh[idx];
}

// ubig[h][col]: col<1280 Ui[k][h][d]; <2560 Uc; <2688 Uf[h][d]; <2816 Uo; else Wa.
__global__ __launch_bounds__(256) void prep_ubig(const float* __restrict__ Ui, const float* __restrict__ Uc,
                                                 const float* __restrict__ Uf, const float* __restrict__ Uo,
                                                 const float* __restrict__ Wa, float* __restrict__ ubig){
  int idx = blockIdx.x*256 + threadIdx.x;
  if (idx >= SZ_UBIG) return;
  int col = idx % NCOL; int h = idx / NCOL;
  float v;
  if (col < 1280){ int k = col >> 7, d = col & 127; v = Ui[(k*HH + h)*HH + d]; }
  else if (col < 2560){ int c2 = col - 1280; int k = c2 >> 7, d = c2 & 127; v = Uc[(k*HH + h)*HH + d]; }
  else if (col < 2688){ v = Uf[h*HH + (col - 2560)]; }
  else if (col < 2816){ v = Uo[h*HH + (col - 2688)]; }
  else               { v = Wa[h*HH + (col - 2816)]; }
  ubig[idx] = v;
}

// ---------------- phase B: fused 10x LSTM scan ----------------
__global__ __launch_bounds__(512) void lstm_scan(const float* __restrict__ feat, const float* __restrict__ w2t,
                                                 const float* __restrict__ bias2, float* __restrict__ tilde){
  int p = blockIdx.x;                 // 0..159
  int g = (p & 7) * 20 + (p >> 3);
  int s = g >> 4; int rb = g & 15; int b0 = rb * 8;
  int tid = threadIdx.x;
  __shared__ float z[8][ZK];
  __shared__ float gl[8][G4];
  const float* w2ts = w2t + (size_t)s*ZK*G4;
  float bj = bias2[s*G4 + tid];
  float c0 = 0.f, c1 = 0.f;
  {
    int q = tid*2; int r = q >> 7; int k = q & 127;
    z[r][128+k] = 0.f; z[r][128+k+1] = 0.f;
    const float* xrow = feat + ((s*TT + 0)*BB + (b0+r))*II;
    float2 xv = *(const float2*)(xrow + k);
    z[r][k] = xv.x; z[r][k+1] = xv.y;
  }
  __syncthreads();
  for (int t = 0; t < TT; ++t){
    float acc[8];
    #pragma unroll
    for (int r=0;r<8;++r) acc[r] = bj;
    for (int kk4 = 0; kk4 < 64; ++kk4){
      float4 wv = *(const float4*)&w2ts[(kk4*G4 + tid)*4];
      #pragma unroll
      for (int r=0;r<8;++r){
        float4 zv = *(const float4*)&z[r][kk4*4];
        acc[r] = fmaf(zv.w, wv.w, fmaf(zv.z, wv.z, fmaf(zv.y, wv.y, fmaf(zv.x, wv.x, acc[r]))));
      }
    }
    int gtype = tid >> 7;
    #pragma unroll
    for (int r=0;r<8;++r){
      float v = acc[r];
      v = (gtype == 2) ? tanhf(v) : sigf(v);
      gl[r][tid] = v;
    }
    __syncthreads();
    {
      int q = tid*2; int r = q >> 7; int k = q & 127;
      float si0 = gl[r][k],     si1 = gl[r][k+1];
      float sf0 = gl[r][128+k], sf1 = gl[r][128+k+1];
      float tg0 = gl[r][256+k], tg1 = gl[r][256+k+1];
      float so0 = gl[r][384+k], so1 = gl[r][384+k+1];
      c0 = sf0*c0 + si0*tg0;
      c1 = sf1*c1 + si1*tg1;
      float h0 = so0*tanhf(c0), h1 = so1*tanhf(c1);
      z[r][128+k] = h0; z[r][128+k+1] = h1;
      float2 tv = make_float2(fmaxf(h0,0.f), fmaxf(h1,0.f));
      *(float2*)&tilde[((s*TT + t)*BB + (b0+r))*HH + k] = tv;
      if (t+1 < TT){
        const float* xrow = feat + ((s*TT + (t+1))*BB + (b0+r))*II;
        float2 xv = *(const float2*)(xrow + k);
        z[r][k] = xv.x; z[r][k+1] = xv.y;
      }
    }
    __syncthreads();
  }
}

// ---------------- phase C: projections ----------------
__global__ __launch_bounds__(256) void proj_ic(const float* __restrict__ tilde,
                                               const float* __restrict__ Wi, const float* __restrict__ bi,
                                               const float* __restrict__ Wc, const float* __restrict__ bc,
                                               float* __restrict__ xi, float* __restrict__ xc){
  const int k = blockIdx.y;
  const int isc = blockIdx.z;
  const float* W = (isc ? Wc : Wi) + k*HH*HH;
  const float* bias = (isc ? bc : bi) + k*HH;
  float* out = isc ? xc : xi;
  const int m0 = blockIdx.x * 128;
  const int tid = threadIdx.x;
  __shared__ float Wl[HH*HH];
  __shared__ float Al[32*HH];
  for (int u = 0; u < 64; ++u) Wl[u*256 + tid] = W[u*256 + tid];
  const int tx = tid & 31, ty = tid >> 5;
  const int d0 = tx*4;
  float4 bv = *(const float4*)&bias[d0];
  __syncthreads();
  for (int ch = 0; ch < 4; ++ch){
    const float* Arow = tilde + (size_t)(k*TT*BB + m0 + ch*32)*HH;
    #pragma unroll
    for (int u = 0; u < 4; ++u)
      *(float4*)&Al[u*1024 + tid*4] = *(const float4*)&Arow[u*1024 + tid*4];
    __syncthreads();
    float4 a0 = bv, a1 = bv, a2 = bv, a3 = bv;
    for (int h = 0; h < HH; ++h){
      float4 w4 = *(const float4*)&Wl[h*HH + d0];
      float A0 = Al[(ty   )*HH + h], A1 = Al[(ty+ 8)*HH + h];
      float A2 = Al[(ty+16)*HH + h], A3 = Al[(ty+24)*HH + h];
      a0.x = fmaf(A0,w4.x,a0.x); a0.y = fmaf(A0,w4.y,a0.y); a0.z = fmaf(A0,w4.z,a0.z); a0.w = fmaf(A0,w4.w,a0.w);
      a1.x = fmaf(A1,w4.x,a1.x); a1.y = fmaf(A1,w4.y,a1.y); a1.z = fmaf(A1,w4.z,a1.z); a1.w = fmaf(A1,w4.w,a1.w);
      a2.x = fmaf(A2,w4.x,a2.x); a2.y = fmaf(A2,w4.y,a2.y); a2.z = fmaf(A2,w4.z,a2.z); a2.w = fmaf(A2,w4.w,a2.w);
      a3.x = fmaf(A3,w4.x,a3.x); a3.y = fmaf(A3,w4.y,a3.y); a3.z = fmaf(A3,w4.z,a3.z); a3.w = fmaf(A3,w4.w,a3.w);
    }
    float4 accs[4] = {a0,a1,a2,a3};
    #pragma unroll
    for (int i = 0; i < 4; ++i){
      int m = m0 + ch*32 + ty + 8*i;
      int t = m >> 7, b = m & 127;
      *(float4*)&out[((t*SS + k)*BB + b)*HH + d0] = accs[i];
    }
    __syncthreads();
  }
}

__global__ __launch_bounds__(256) void proj_fo(const float* __restrict__ tilde,
                                               const float* __restrict__ Wf, const float* __restrict__ bf,
                                               const float* __restrict__ Wo, const float* __restrict__ bo,
                                               float* __restrict__ xf, float* __restrict__ xo){
  const int iso = blockIdx.y;
  const float* W = iso ? Wo : Wf;
  const float* bias = iso ? bo : bf;
  float* out = iso ? xo : xf;
  const int m0 = blockIdx.x * 128;
  const int tid = threadIdx.x;
  __shared__ float Wl[HH*HH];
  __shared__ float Al[32*HH];
  for (int u = 0; u < 64; ++u) Wl[u*256 + tid] = W[u*256 + tid];
  const int tx = tid & 31, ty = tid >> 5;
  const int d0 = tx*4;
  float4 bv = *(const float4*)&bias[d0];
  __syncthreads();
  for (int ch = 0; ch < 4; ++ch){
    const float* Arow = tilde + (size_t)(m0 + ch*32)*HH;
    #pragma unroll
    for (int u = 0; u < 4; ++u)
      *(float4*)&Al[u*1024 + tid*4] = *(const float4*)&Arow[u*1024 + tid*4];
    __syncthreads();
    float4 a0 = bv, a1 = bv, a2 = bv, a3 = bv;
    for (int h = 0; h < HH; ++h){
      float4 w4 = *(const float4*)&Wl[h*HH + d0];
      float A0 = Al[(ty   )*HH + h], A1 = Al[(ty+ 8)*HH + h];
      float A2 = Al[(ty+16)*HH + h], A3 = Al[(ty+24)*HH + h];
      a0.x = fmaf(A0,w4.x,a0.x); a0.y = fmaf(A0,w4.y,a0.y); a0.z = fmaf(A0,w4.z,a0.z); a0.w = fmaf(A0,w4.w,a0.w);
      a1.x = fmaf(A1,w4.x,a1.x); a1.y = fmaf(A1,w4.y,a1.y); a1.z = fmaf(A1,w4.z,a1.z); a1.w = fmaf(A1,w4.w,a1.w);
      a2.x = fmaf(A2,w4.x,a2.x); a2.y = fmaf(A2,w4.y,a2.y); a2.z = fmaf(A2,w4.z,a2.z); a2.w = fmaf(A2,w4.w,a2.w);
      a3.x = fmaf(A3,w4.x,a3.x); a3.y = fmaf(A3,w4.y,a3.y); a3.z = fmaf(A3,w4.z,a3.z); a3.w = fmaf(A3,w4.w,a3.w);
    }
    float4 accs[4] = {a0,a1,a2,a3};
    #pragma unroll
    for (int i = 0; i < 4; ++i){
      int m = m0 + ch*32 + ty + 8*i;
      *(float4*)&out[(size_t)m*HH + d0] = accs[i];
    }
    __syncthreads();
  }
}

// ---------------- phase D: cooperative weight-stationary MI-LSTM scan ----------------
// Barrier with NO cache-wide maintenance: all cross-block data moves via
// sc0/sc1 per-access-coherent atomics; each wave drains vmcnt before arrival.
__device__ __forceinline__ void gbar(int* cnt, int target){
  asm volatile("s_waitcnt vmcnt(0)" ::: "memory");
  __syncthreads();
  if (threadIdx.x == 0){
    __hip_atomic_fetch_add(cnt, 1, __ATOMIC_RELAXED, __HIP_MEMORY_SCOPE_AGENT);
    while (__hip_atomic_load(cnt, __ATOMIC_RELAXED, __HIP_MEMORY_SCOPE_AGENT) < target)
      __builtin_amdgcn_s_sleep(1);
  }
  __syncthreads();
}

__global__ void zero_cnt(int* cnt){ if (threadIdx.x == 0) *cnt = 0; }

// 92 blocks x 512 threads (cooperative). Block bk owns 32 Ubig columns
// (16KB f32, LDS-resident for the whole scan). Per step:
//   [x-prefetch to regs (rows r0..r0+3)] [stage h/c -> LDS via sc1 loads]
//   [4x4 register-tiled GEMM on 256 threads] -> act (sc1 stores) -> barrier ->
//   pointwise (blocks 0..63, 2 rows each; sc1 loads/stores) -> barrier.
__global__ __launch_bounds__(512) void mi_coop(
    const float* __restrict__ ubig,
    const float* __restrict__ xi, const float* __restrict__ xc,
    const float* __restrict__ xf, const float* __restrict__ xo,
    const float* __restrict__ headW, const float* __restrict__ headb,
    float* hT, float* cT,
    float* act, int* cnt, float* __restrict__ out)
{
  const int bk = blockIdx.x;
  const int tid = threadIdx.x;
  __shared__ float Wl[128*32];                 // 16KB weights, persistent
  __shared__ __align__(16) float avL[128*128]; // 64KB h (or c) stage, [d][b]
  __shared__ float lL[20*128];                 // P: l[row][k][d]
  __shared__ float part[8][8];
  __shared__ float uL[2][10];
  const int col = tid & 31, rg = tid >> 5;
  const int gcol = bk*32 + col;
  for (int h = rg; h < 128; h += 16) Wl[h*32 + col] = ubig[(size_t)h*NCOL + gcol];

  int btype;
  if (bk < 40) btype = 0; else if (bk < 80) btype = 1;
  else if (bk < 84) btype = 2; else if (bk < 88) btype = 3; else btype = 4;

  // compute-thread (tid<256) output tile: rows r0..r0+3, block-local cols c0..c0+3
  const int cq = tid >> 5;      // 0..7 valid for tid<256
  const int rq = tid & 31;
  const int c0 = cq*4, r0 = rq*4;
  const float* xbase = nullptr; size_t xstep = 0;
  if (tid < 256 && btype != 4){
    if (btype == 0){ int k = bk >> 2; int dloc = (bk & 3)*32 + c0;
      xbase = xi + ((size_t)k*BB + r0)*HH + dloc; xstep = (size_t)SS*BB*HH; }
    else if (btype == 1){ int k = (bk-40) >> 2; int dloc = ((bk-40) & 3)*32 + c0;
      xbase = xc + ((size_t)k*BB + r0)*HH + dloc; xstep = (size_t)SS*BB*HH; }
    else if (btype == 2){ int dloc = (bk-80)*32 + c0;
      xbase = xf + (size_t)r0*HH + dloc; xstep = (size_t)BB*HH; }
    else { int dloc = (bk-84)*32 + c0;
      xbase = xo + (size_t)r0*HH + dloc; xstep = (size_t)BB*HH; }
  }

  const int prow = tid >> 8, pd = tid & 127, phalf = (tid >> 7) & 1;
  const int pb = bk*2 + prow;
  const bool isP = (bk < 64);
  float c_reg = 0.f;
  float hw = headW[pd];
  float hb = headb[0];
  if (isP && phalf == 0){ ast(&hT[pd*BB + pb], 0.f); ast(&cT[pd*BB + pb], 0.f); }

  int phase = 1;
  gbar(cnt, (phase++)*NBLK);

  for (int t = 0; t < TT; ++t){
    // ---------- x prefetch (consumed after GEMM) ----------
    float4 xv[4];
    if (tid < 256 && btype != 4){
      const float* xp = xbase + (size_t)t*xstep;
      xv[0] = *(const float4*)(xp);
      xv[1] = *(const float4*)(xp + HH);
      xv[2] = *(const float4*)(xp + 2*HH);
      xv[3] = *(const float4*)(xp + 3*HH);
    } else {
      xv[0] = xv[1] = xv[2] = xv[3] = make_float4(0.f,0.f,0.f,0.f);
    }
    // ---------- stage state (all 512 threads, sc1 coherent loads) ----------
    const float* src = (btype == 4) ? cT : hT;
    #pragma unroll
    for (int u = 0; u < 32; ++u)
      avL[u*512 + tid] = ald(&src[u*512 + tid]);
    __syncthreads();
    // ---------- G: 4x4 register-tiled GEMM ----------
    if (tid < 256){
      float acc[4][4] = {{0.f,0.f,0.f,0.f},{0.f,0.f,0.f,0.f},{0.f,0.f,0.f,0.f},{0.f,0.f,0.f,0.f}};
      #pragma unroll 2
      for (int d = 0; d < 128; ++d){
        float4 av = *(const float4*)&avL[d*128 + r0];
        float4 wv = *(const float4*)&Wl[d*32 + c0];
        float a[4] = {av.x, av.y, av.z, av.w};
        float w[4] = {wv.x, wv.y, wv.z, wv.w};
        #pragma unroll
        for (int i = 0; i < 4; ++i)
          #pragma unroll
          for (int j = 0; j < 4; ++j)
            acc[i][j] = fmaf(a[i], w[j], acc[i][j]);
      }
      #pragma unroll
      for (int i = 0; i < 4; ++i){
        float px[4] = {xv[i].x, xv[i].y, xv[i].z, xv[i].w};
        #pragma unroll
        for (int j = 0; j < 4; ++j){
          float pv = acc[i][j] + px[j];
          float v;
          if (btype == 1) v = tanhf(pv);
          else if (btype == 4) v = pv;
          else v = sigf(pv);
          ast(&act[(size_t)(r0 + i)*NCOL + (size_t)bk*32 + c0 + j], v);
        }
      }
    }
    gbar(cnt, (phase++)*NBLK);
    // ---------- P: attention + cell update (blocks 0..63, 2 rows each) ----------
    const float* arow = act + (size_t)(isP ? pb : 0)*NCOL;
    if (isP){
      float cw = ald(&arow[2816 + pd]);
      float s5[5];
      #pragma unroll
      for (int j = 0; j < 5; ++j){
        int k = phalf + 2*j;
        float li = ald(&arow[k*128 + pd]) * ald(&arow[1280 + k*128 + pd]);
        lL[(prow*10 + k)*128 + pd] = li;
        s5[j] = li * cw;
      }
      #pragma unroll
      for (int j = 0; j < 5; ++j){
        float s = s5[j];
        s += __shfl_down(s, 32); s += __shfl_down(s, 16); s += __shfl_down(s, 8);
        s += __shfl_down(s, 4);  s += __shfl_down(s, 2);  s += __shfl_down(s, 1);
        if ((tid & 63) == 0) part[tid >> 6][j] = s;
      }
    }
    __syncthreads();
    if (isP && tid < 20){
      int row = tid / 10, k = tid - row*10;
      int wbase = row*4 + (k & 1)*2;
      uL[row][k] = tanhf(part[wbase][k >> 1] + part[wbase + 1][k >> 1]);
    }
    __syncthreads();
    if (isP){
      float m = uL[prow][0];
      #pragma unroll
      for (int k = 1; k < 10; ++k) m = fmaxf(m, uL[prow][k]);
      float e[10]; float es = 0.f;
      #pragma unroll
      for (int k = 0; k < 10; ++k){ e[k] = expf(uL[prow][k] - m); es += e[k]; }
      float inv = 1.f / es;
      float sh = 0.f;
      if (phalf == 0){
        float lm = 0.f;
        #pragma unroll
        for (int k = 0; k < 10; ++k) lm = fmaf(e[k]*inv, lL[(prow*10 + k)*128 + pd], lm);
        float f = ald(&arow[2560 + pd]);
        float o = ald(&arow[2688 + pd]);
        float cn = fmaf(f, c_reg, lm);
        float hn = o * tanhf(cn);
        c_reg = cn;
        ast(&hT[pd*BB + pb], hn);
        ast(&cT[pd*BB + pb], cn);
        sh = fmaxf(hn, 0.f) * hw;
      }
      float s = sh;
      s += __shfl_down(s, 32); s += __shfl_down(s, 16); s += __shfl_down(s, 8);
      s += __shfl_down(s, 4);  s += __shfl_down(s, 2);  s += __shfl_down(s, 1);
      if ((tid & 63) == 0) part[tid >> 6][6] = s;
    }
    __syncthreads();
    if (isP && tid < 2){
      float s = part[tid*4][6] + part[tid*4 + 1][6];
      out[t*BB + bk*2 + tid] = fmaxf(s + hb, 0.f);
    }
    gbar(cnt, (phase++)*NBLK);
  }
}

extern "C" void kernel_launch(void* const* d_in, const int* in_sizes, int n_in,
                              void* d_out, int out_size, void* d_ws, size_t ws_size,
                              hipStream_t stream) {
  const float* feat  = (const float*)d_in[0];
  const float* Wih   = (const float*)d_in[1];
  const float* Whh   = (const float*)d_in[2];
  const float* bih   = (const float*)d_in[3];
  const float* bhh   = (const float*)d_in[4];
  const float* miWi  = (const float*)d_in[5];
  const float* miUi  = (const float*)d_in[6];
  const float* mibi  = (const float*)d_in[7];
  const float* miWc  = (const float*)d_in[8];
  const float* miUc  = (const float*)d_in[9];
  const float* mibc  = (const float*)d_in[10];
  const float* miWf  = (const float*)d_in[11];
  const float* miUf  = (const float*)d_in[12];
  const float* mibf  = (const float*)d_in[13];
  const float* miWo  = (const float*)d_in[14];
  const float* miUo  = (const float*)d_in[15];
  const float* mibo  = (const float*)d_in[16];
  const float* miWa  = (const float*)d_in[17];
  const float* headW = (const float*)d_in[18];
  const float* headb = (const float*)d_in[19];
  float* out = (float*)d_out;

  float* ws    = (float*)d_ws;
  float* w2t   = ws + OFF_W2T;
  float* bias2 = ws + OFF_BIAS2;
  float* ubig  = ws + OFF_UBIG;
  float* tilde = ws + OFF_TILDE;
  float* xi    = ws + OFF_XI;
  float* xc    = ws + OFF_XC;
  float* xf    = ws + OFF_XF;
  float* xo    = ws + OFF_XO;
  float* hT    = ws + OFF_HT;
  float* cT    = ws + OFF_CT;
  float* act   = ws + OFF_ACT;
  int*   cnt   = (int*)(ws + OFF_CNT);

  prep_w2t<<<dim3(SZ_W2T/256), dim3(256), 0, stream>>>(Wih, Whh, bih, bhh, w2t, bias2);
  prep_ubig<<<dim3((SZ_UBIG+255)/256), dim3(256), 0, stream>>>(miUi, miUc, miUf, miUo, miWa, ubig);
  zero_cnt<<<dim3(1), dim3(64), 0, stream>>>(cnt);
  lstm_scan<<<dim3(160), dim3(512), 0, stream>>>(feat, w2t, bias2, tilde);
  proj_ic<<<dim3(256, SS, 2), dim3(256), 0, stream>>>(tilde, miWi, mibi, miWc, mibc, xi, xc);
  proj_fo<<<dim3(256, 2), dim3(256), 0, stream>>>(tilde, miWf, mibf, miWo, mibo, xf, xo);

  void* kargs[] = { (void*)&ubig, (void*)&xi, (void*)&xc, (void*)&xf, (void*)&xo,
                    (void*)&headW, (void*)&headb, (void*)&hT, (void*)&cT,
                    (void*)&act, (void*)&cnt, (void*)&out };
  hipLaunchCooperativeKernel((const void*)mi_coop, dim3(NBLK), dim3(512), kargs, 0, stream);
}

// Round 8
// 8929.621 us; speedup vs baseline: 1.3039x; 1.3039x over previous
//
#include <hip/hip_runtime.h>
#include <math.h>

// Model: 10 parallel LSTMs -> MI-LSTM w/ stream attention -> linear head.
// All f32 (no fp32-input MFMA on CDNA4; accuracy threshold requires f32).
//
#define SS 10
#define TT 256
#define BB 128
#define HH 128
#define II 128
#define G4 512     // 4H
#define ZK 256     // I + H (fused [x|h] contraction)
#define NCOL 2944  // phase-D fused weight columns: Ui(1280)|Uc(1280)|Uf(128)|Uo(128)|Wa(128)
#define NBLK 92    // cooperative blocks: 92 x 32 cols = 2944

#define SZ_W2T   (SS*ZK*G4)        // 1,310,720
#define SZ_BIAS2 (SS*G4)           // 5,120
#define SZ_UBIG  (HH*NCOL)         // 376,832
#define SZ_TILDE (SS*TT*BB*HH)     // 41,943,040
#define SZ_X     (TT*SS*BB*HH)     // 41,943,040
#define SZ_XFO   (TT*BB*HH)        // 4,194,304

#define OFF_W2T   0
#define OFF_BIAS2 (OFF_W2T + SZ_W2T)
#define OFF_UBIG  (OFF_BIAS2 + SZ_BIAS2)
#define OFF_TILDE (OFF_UBIG + SZ_UBIG)
#define OFF_XI    (OFF_TILDE + SZ_TILDE)
#define OFF_XC    (OFF_XI + SZ_X)
#define OFF_XF    (OFF_XC + SZ_X)
#define OFF_XO    (OFF_XF + SZ_XFO)
#define OFF_HT    (OFF_XO + SZ_XFO)
#define OFF_CT    (OFF_HT + BB*HH)
#define OFF_ACT   (OFF_CT + BB*HH)
#define OFF_CNT   (OFF_ACT + BB*NCOL)

__device__ __forceinline__ float sigf(float x){ return 1.0f/(1.0f+expf(-x)); }

// per-access coherent ops (sc0/sc1 path; no cache-wide wb/inv)
__device__ __forceinline__ float ald(const float* p){
  return __hip_atomic_load(p, __ATOMIC_RELAXED, __HIP_MEMORY_SCOPE_AGENT);
}
__device__ __forceinline__ void ast(float* p, float v){
  __hip_atomic_store(p, v, __ATOMIC_RELAXED, __HIP_MEMORY_SCOPE_AGENT);
}
__device__ __forceinline__ unsigned long long ald2(const unsigned long long* p){
  return __hip_atomic_load(p, __ATOMIC_RELAXED, __HIP_MEMORY_SCOPE_AGENT);
}
// 16B coherent store (full-line coverage when 4 consecutive per thread).
// ext_vector_type binds to a VGPR quad directly (HIP float4 is a struct and cannot).
typedef float f32x4v __attribute__((ext_vector_type(4)));
__device__ __forceinline__ void ast4(float* p, float a, float b, float c, float d){
  f32x4v w; w.x = a; w.y = b; w.z = c; w.w = d;
  asm volatile("global_store_dwordx4 %0, %1, off sc0 sc1" :: "v"(p), "v"(w) : "memory");
}

// ---------------- prep: fused transposed LSTM weights (b128-friendly) ----------------
__global__ __launch_bounds__(256) void prep_w2t(const float* __restrict__ Wih, const float* __restrict__ Whh,
                                                const float* __restrict__ bih, const float* __restrict__ bhh,
                                                float* __restrict__ w2t, float* __restrict__ bias2){
  int idx = blockIdx.x*256 + threadIdx.x;
  if (idx < SZ_W2T){
    int q = idx & 3; int j = (idx >> 2) & 511; int kk4 = (idx >> 11) & 63; int s = idx >> 17;
    int kk = kk4*4 + q;
    float v = (kk < II) ? Wih[(s*G4 + j)*II + kk] : Whh[(s*G4 + j)*HH + (kk - II)];
    w2t[idx] = v;
  }
  if (idx < SZ_BIAS2) bias2[idx] = bih[idx] + bhh[idx];
}

__global__ __launch_bounds__(256) void prep_ubig(const float* __restrict__ Ui, const float* __restrict__ Uc,
                                                 const float* __restrict__ Uf, const float* __restrict__ Uo,
                                                 const float* __restrict__ Wa, float* __restrict__ ubig){
  int idx = blockIdx.x*256 + threadIdx.x;
  if (idx >= SZ_UBIG) return;
  int col = idx % NCOL; int h = idx / NCOL;
  float v;
  if (col < 1280){ int k = col >> 7, d = col & 127; v = Ui[(k*HH + h)*HH + d]; }
  else if (col < 2560){ int c2 = col - 1280; int k = c2 >> 7, d = c2 & 127; v = Uc[(k*HH + h)*HH + d]; }
  else if (col < 2688){ v = Uf[h*HH + (col - 2560)]; }
  else if (col < 2816){ v = Uo[h*HH + (col - 2688)]; }
  else               { v = Wa[h*HH + (col - 2816)]; }
  ubig[idx] = v;
}

// ---------------- phase B: fused 10x LSTM scan (unchanged) ----------------
__global__ __launch_bounds__(512) void lstm_scan(const float* __restrict__ feat, const float* __restrict__ w2t,
                                                 const float* __restrict__ bias2, float* __restrict__ tilde){
  int p = blockIdx.x;                 // 0..159
  int g = (p & 7) * 20 + (p >> 3);
  int s = g >> 4; int rb = g & 15; int b0 = rb * 8;
  int tid = threadIdx.x;
  __shared__ float z[8][ZK];
  __shared__ float gl[8][G4];
  const float* w2ts = w2t + (size_t)s*ZK*G4;
  float bj = bias2[s*G4 + tid];
  float c0 = 0.f, c1 = 0.f;
  {
    int q = tid*2; int r = q >> 7; int k = q & 127;
    z[r][128+k] = 0.f; z[r][128+k+1] = 0.f;
    const float* xrow = feat + ((s*TT + 0)*BB + (b0+r))*II;
    float2 xv = *(const float2*)(xrow + k);
    z[r][k] = xv.x; z[r][k+1] = xv.y;
  }
  __syncthreads();
  for (int t = 0; t < TT; ++t){
    float acc[8];
    #pragma unroll
    for (int r=0;r<8;++r) acc[r] = bj;
    for (int kk4 = 0; kk4 < 64; ++kk4){
      float4 wv = *(const float4*)&w2ts[(kk4*G4 + tid)*4];
      #pragma unroll
      for (int r=0;r<8;++r){
        float4 zv = *(const float4*)&z[r][kk4*4];
        acc[r] = fmaf(zv.w, wv.w, fmaf(zv.z, wv.z, fmaf(zv.y, wv.y, fmaf(zv.x, wv.x, acc[r]))));
      }
    }
    int gtype = tid >> 7;
    #pragma unroll
    for (int r=0;r<8;++r){
      float v = acc[r];
      v = (gtype == 2) ? tanhf(v) : sigf(v);
      gl[r][tid] = v;
    }
    __syncthreads();
    {
      int q = tid*2; int r = q >> 7; int k = q & 127;
      float si0 = gl[r][k],     si1 = gl[r][k+1];
      float sf0 = gl[r][128+k], sf1 = gl[r][128+k+1];
      float tg0 = gl[r][256+k], tg1 = gl[r][256+k+1];
      float so0 = gl[r][384+k], so1 = gl[r][384+k+1];
      c0 = sf0*c0 + si0*tg0;
      c1 = sf1*c1 + si1*tg1;
      float h0 = so0*tanhf(c0), h1 = so1*tanhf(c1);
      z[r][128+k] = h0; z[r][128+k+1] = h1;
      float2 tv = make_float2(fmaxf(h0,0.f), fmaxf(h1,0.f));
      *(float2*)&tilde[((s*TT + t)*BB + (b0+r))*HH + k] = tv;
      if (t+1 < TT){
        const float* xrow = feat + ((s*TT + (t+1))*BB + (b0+r))*II;
        float2 xv = *(const float2*)(xrow + k);
        z[r][k] = xv.x; z[r][k+1] = xv.y;
      }
    }
    __syncthreads();
  }
}

// ---------------- phase C: projections (unchanged) ----------------
__global__ __launch_bounds__(256) void proj_ic(const float* __restrict__ tilde,
                                               const float* __restrict__ Wi, const float* __restrict__ bi,
                                               const float* __restrict__ Wc, const float* __restrict__ bc,
                                               float* __restrict__ xi, float* __restrict__ xc){
  const int k = blockIdx.y;
  const int isc = blockIdx.z;
  const float* W = (isc ? Wc : Wi) + k*HH*HH;
  const float* bias = (isc ? bc : bi) + k*HH;
  float* out = isc ? xc : xi;
  const int m0 = blockIdx.x * 128;
  const int tid = threadIdx.x;
  __shared__ float Wl[HH*HH];
  __shared__ float Al[32*HH];
  for (int u = 0; u < 64; ++u) Wl[u*256 + tid] = W[u*256 + tid];
  const int tx = tid & 31, ty = tid >> 5;
  const int d0 = tx*4;
  float4 bv = *(const float4*)&bias[d0];
  __syncthreads();
  for (int ch = 0; ch < 4; ++ch){
    const float* Arow = tilde + (size_t)(k*TT*BB + m0 + ch*32)*HH;
    #pragma unroll
    for (int u = 0; u < 4; ++u)
      *(float4*)&Al[u*1024 + tid*4] = *(const float4*)&Arow[u*1024 + tid*4];
    __syncthreads();
    float4 a0 = bv, a1 = bv, a2 = bv, a3 = bv;
    for (int h = 0; h < HH; ++h){
      float4 w4 = *(const float4*)&Wl[h*HH + d0];
      float A0 = Al[(ty   )*HH + h], A1 = Al[(ty+ 8)*HH + h];
      float A2 = Al[(ty+16)*HH + h], A3 = Al[(ty+24)*HH + h];
      a0.x = fmaf(A0,w4.x,a0.x); a0.y = fmaf(A0,w4.y,a0.y); a0.z = fmaf(A0,w4.z,a0.z); a0.w = fmaf(A0,w4.w,a0.w);
      a1.x = fmaf(A1,w4.x,a1.x); a1.y = fmaf(A1,w4.y,a1.y); a1.z = fmaf(A1,w4.z,a1.z); a1.w = fmaf(A1,w4.w,a1.w);
      a2.x = fmaf(A2,w4.x,a2.x); a2.y = fmaf(A2,w4.y,a2.y); a2.z = fmaf(A2,w4.z,a2.z); a2.w = fmaf(A2,w4.w,a2.w);
      a3.x = fmaf(A3,w4.x,a3.x); a3.y = fmaf(A3,w4.y,a3.y); a3.z = fmaf(A3,w4.z,a3.z); a3.w = fmaf(A3,w4.w,a3.w);
    }
    float4 accs[4] = {a0,a1,a2,a3};
    #pragma unroll
    for (int i = 0; i < 4; ++i){
      int m = m0 + ch*32 + ty + 8*i;
      int t = m >> 7, b = m & 127;
      *(float4*)&out[((t*SS + k)*BB + b)*HH + d0] = accs[i];
    }
    __syncthreads();
  }
}

__global__ __launch_bounds__(256) void proj_fo(const float* __restrict__ tilde,
                                               const float* __restrict__ Wf, const float* __restrict__ bf,
                                               const float* __restrict__ Wo, const float* __restrict__ bo,
                                               float* __restrict__ xf, float* __restrict__ xo){
  const int iso = blockIdx.y;
  const float* W = iso ? Wo : Wf;
  const float* bias = iso ? bo : bf;
  float* out = iso ? xo : xf;
  const int m0 = blockIdx.x * 128;
  const int tid = threadIdx.x;
  __shared__ float Wl[HH*HH];
  __shared__ float Al[32*HH];
  for (int u = 0; u < 64; ++u) Wl[u*256 + tid] = W[u*256 + tid];
  const int tx = tid & 31, ty = tid >> 5;
  const int d0 = tx*4;
  float4 bv = *(const float4*)&bias[d0];
  __syncthreads();
  for (int ch = 0; ch < 4; ++ch){
    const float* Arow = tilde + (size_t)(m0 + ch*32)*HH;
    #pragma unroll
    for (int u = 0; u < 4; ++u)
      *(float4*)&Al[u*1024 + tid*4] = *(const float4*)&Arow[u*1024 + tid*4];
    __syncthreads();
    float4 a0 = bv, a1 = bv, a2 = bv, a3 = bv;
    for (int h = 0; h < HH; ++h){
      float4 w4 = *(const float4*)&Wl[h*HH + d0];
      float A0 = Al[(ty   )*HH + h], A1 = Al[(ty+ 8)*HH + h];
      float A2 = Al[(ty+16)*HH + h], A3 = Al[(ty+24)*HH + h];
      a0.x = fmaf(A0,w4.x,a0.x); a0.y = fmaf(A0,w4.y,a0.y); a0.z = fmaf(A0,w4.z,a0.z); a0.w = fmaf(A0,w4.w,a0.w);
      a1.x = fmaf(A1,w4.x,a1.x); a1.y = fmaf(A1,w4.y,a1.y); a1.z = fmaf(A1,w4.z,a1.z); a1.w = fmaf(A1,w4.w,a1.w);
      a2.x = fmaf(A2,w4.x,a2.x); a2.y = fmaf(A2,w4.y,a2.y); a2.z = fmaf(A2,w4.z,a2.z); a2.w = fmaf(A2,w4.w,a2.w);
      a3.x = fmaf(A3,w4.x,a3.x); a3.y = fmaf(A3,w4.y,a3.y); a3.z = fmaf(A3,w4.z,a3.z); a3.w = fmaf(A3,w4.w,a3.w);
    }
    float4 accs[4] = {a0,a1,a2,a3};
    #pragma unroll
    for (int i = 0; i < 4; ++i){
      int m = m0 + ch*32 + ty + 8*i;
      *(float4*)&out[(size_t)m*HH + d0] = accs[i];
    }
    __syncthreads();
  }
}

// ---------------- phase D: cooperative weight-stationary MI-LSTM scan ----------------
// Relaxed barrier (no cache-wide wb/inv): sc1 per-access coherence everywhere,
// each wave drains vmcnt before arrival.
__device__ __forceinline__ void gbar(int* cnt, int target){
  asm volatile("s_waitcnt vmcnt(0)" ::: "memory");
  __syncthreads();
  if (threadIdx.x == 0){
    __hip_atomic_fetch_add(cnt, 1, __ATOMIC_RELAXED, __HIP_MEMORY_SCOPE_AGENT);
    while (__hip_atomic_load(cnt, __ATOMIC_RELAXED, __HIP_MEMORY_SCOPE_AGENT) < target)
      __builtin_amdgcn_s_sleep(1);
  }
  __syncthreads();
}

__global__ void zero_cnt(int* cnt){ if (threadIdx.x == 0) *cnt = 0; }

// 92 blocks x 512 threads. Block bk owns 32 Ubig columns (16KB LDS, persistent).
// hR/cR are ROW-major [b][d] (coalesced sc1 traffic both directions).
// Per step: [stage hR->hL (straight copy, 16B-granule XOR swizzle)] ->
// [4x4 GEMM, swizzled b128 A reads] -> [panel transpose in LDS] ->
// [x-add + activation + full-line dwordx4 sc1 act stores] -> bar -> P -> bar.
__global__ __launch_bounds__(512) void mi_coop(
    const float* __restrict__ ubig,
    const float* __restrict__ xi, const float* __restrict__ xc,
    const float* __restrict__ xf, const float* __restrict__ xo,
    const float* __restrict__ headW, const float* __restrict__ headb,
    float* hR, float* cR,
    float* act, int* cnt, float* __restrict__ out)
{
  const int bk = blockIdx.x;
  const int tid = threadIdx.x;
  __shared__ float Wl[128*32];                 // 16KB weights, persistent
  __shared__ __align__(16) float hL[128*128];  // 64KB state stage, [b][d^swz]
  __shared__ float pan[128*33];                // 16.9KB raw-gate panel (padded)
  __shared__ float lL[20*128];
  __shared__ float part[8][8];
  __shared__ float uL[2][10];
  const int col = tid & 31, rg5 = tid >> 5;
  const int gcol = bk*32 + col;
  for (int h = rg5; h < 128; h += 16) Wl[h*32 + col] = ubig[(size_t)h*NCOL + gcol];

  int btype;
  if (bk < 40) btype = 0; else if (bk < 80) btype = 1;
  else if (bk < 84) btype = 2; else if (bk < 88) btype = 3; else btype = 4;

  // GEMM tile: rows r0..r0+3, block-local cols c0..c0+3
  const int cq = tid >> 5;        // 0..7 (tid<256)
  const int rq = tid & 31;
  const int c0 = cq*4, r0 = rq*4;
  const int kk = (rq & 7) << 2;   // LDS swizzle key for this thread's rows

  // panel-reader / x / act-store role: 1 row x 16 cols (= one 64B line)
  const int prd_row = tid >> 1, prd_co = (tid & 1) * 16;
  const float* xrd = nullptr; size_t xrd_step = 0;
  if (tid < 256 && btype != 4){
    if (btype == 0){ int k = bk >> 2; int dloc = (bk & 3)*32 + prd_co;
      xrd = xi + ((size_t)k*BB + prd_row)*HH + dloc; xrd_step = (size_t)SS*BB*HH; }
    else if (btype == 1){ int k = (bk-40) >> 2; int dloc = ((bk-40) & 3)*32 + prd_co;
      xrd = xc + ((size_t)k*BB + prd_row)*HH + dloc; xrd_step = (size_t)SS*BB*HH; }
    else if (btype == 2){ int dloc = (bk-80)*32 + prd_co;
      xrd = xf + (size_t)prd_row*HH + dloc; xrd_step = (size_t)BB*HH; }
    else { int dloc = (bk-84)*32 + prd_co;
      xrd = xo + (size_t)prd_row*HH + dloc; xrd_step = (size_t)BB*HH; }
  }

  const int prow = tid >> 8, pd = tid & 127, phalf = (tid >> 7) & 1;
  const int pb = bk*2 + prow;
  const bool isP = (bk < 64);
  float c_reg = 0.f;
  float hw = headW[pd];
  float hb = headb[0];
  if (isP && phalf == 0){ ast(&hR[pb*HH + pd], 0.f); ast(&cR[pb*HH + pd], 0.f); }

  int phase = 1;
  gbar(cnt, (phase++)*NBLK);

  for (int t = 0; t < TT; ++t){
    // ---------- x prefetch (reader-pattern: 16 consecutive cols of one row) ----------
    float4 xv[4];
    if (tid < 256 && btype != 4){
      const float* xp = xrd + (size_t)t*xrd_step;
      xv[0] = *(const float4*)(xp);      xv[1] = *(const float4*)(xp + 4);
      xv[2] = *(const float4*)(xp + 8);  xv[3] = *(const float4*)(xp + 12);
    } else {
      xv[0] = xv[1] = xv[2] = xv[3] = make_float4(0.f,0.f,0.f,0.f);
    }
    // ---------- stage state (row-major copy, coalesced ald2, swizzled LDS) ----------
    // 8192 float2 total: row b = lin>>6 (64 float2/row), d0 = (lin&63)*2.
    const float* src = (btype == 4) ? cR : hR;
    const unsigned long long* src8 = (const unsigned long long*)src;
    unsigned long long sv[16];
    #pragma unroll
    for (int u = 0; u < 16; ++u) sv[u] = ald2(&src8[u*512 + tid]);
    #pragma unroll
    for (int u = 0; u < 16; ++u){
      int lin = u*512 + tid;
      int b = lin >> 6;
      int d0 = (lin & 63) * 2;
      int key = ((b >> 2) & 7) << 2;
      int gran = d0 & ~3, off = d0 & 3;
      *(float2*)&hL[b*128 + (gran ^ key) + off] = *(float2*)&sv[u];
    }
    __syncthreads();
    // ---------- G: 4x4 register-tiled GEMM (swizzled row-major A) ----------
    if (tid < 256){
      float acc[4][4] = {{0.f,0.f,0.f,0.f},{0.f,0.f,0.f,0.f},{0.f,0.f,0.f,0.f},{0.f,0.f,0.f,0.f}};
      for (int d0 = 0; d0 < 128; d0 += 4){
        int dsw = d0 ^ kk;
        float4 av0 = *(const float4*)&hL[(r0+0)*128 + dsw];
        float4 av1 = *(const float4*)&hL[(r0+1)*128 + dsw];
        float4 av2 = *(const float4*)&hL[(r0+2)*128 + dsw];
        float4 av3 = *(const float4*)&hL[(r0+3)*128 + dsw];
        float4 wv0 = *(const float4*)&Wl[(d0+0)*32 + c0];
        float4 wv1 = *(const float4*)&Wl[(d0+1)*32 + c0];
        float4 wv2 = *(const float4*)&Wl[(d0+2)*32 + c0];
        float4 wv3 = *(const float4*)&Wl[(d0+3)*32 + c0];
        float4 avs[4] = {av0, av1, av2, av3};
        float4 wvs[4] = {wv0, wv1, wv2, wv3};
        #pragma unroll
        for (int i = 0; i < 4; ++i){
          float a0 = avs[i].x, a1 = avs[i].y, a2 = avs[i].z, a3 = avs[i].w;
          acc[i][0] = fmaf(a0, wvs[0].x, acc[i][0]); acc[i][1] = fmaf(a0, wvs[0].y, acc[i][1]);
          acc[i][2] = fmaf(a0, wvs[0].z, acc[i][2]); acc[i][3] = fmaf(a0, wvs[0].w, acc[i][3]);
          acc[i][0] = fmaf(a1, wvs[1].x, acc[i][0]); acc[i][1] = fmaf(a1, wvs[1].y, acc[i][1]);
          acc[i][2] = fmaf(a1, wvs[1].z, acc[i][2]); acc[i][3] = fmaf(a1, wvs[1].w, acc[i][3]);
          acc[i][0] = fmaf(a2, wvs[2].x, acc[i][0]); acc[i][1] = fmaf(a2, wvs[2].y, acc[i][1]);
          acc[i][2] = fmaf(a2, wvs[2].z, acc[i][2]); acc[i][3] = fmaf(a2, wvs[2].w, acc[i][3]);
          acc[i][0] = fmaf(a3, wvs[3].x, acc[i][0]); acc[i][1] = fmaf(a3, wvs[3].y, acc[i][1]);
          acc[i][2] = fmaf(a3, wvs[3].z, acc[i][2]); acc[i][3] = fmaf(a3, wvs[3].w, acc[i][3]);
        }
      }
      // raw gates -> padded panel
      #pragma unroll
      for (int i = 0; i < 4; ++i)
        #pragma unroll
        for (int j = 0; j < 4; ++j)
          pan[(r0+i)*33 + c0 + j] = acc[i][j];
    }
    __syncthreads();
    // ---------- panel read + x add + activation + full-line act store ----------
    if (tid < 256){
      float vout[16];
      #pragma unroll
      for (int u = 0; u < 16; ++u){
        float pv = pan[prd_row*33 + prd_co + u] + ((&xv[0].x)[u]);
        float v;
        if (btype == 1) v = tanhf(pv);
        else if (btype == 4) v = pv;
        else v = sigf(pv);
        vout[u] = v;
      }
      float* ap = &act[(size_t)prd_row*NCOL + (size_t)bk*32 + prd_co];
      ast4(ap,      vout[0],  vout[1],  vout[2],  vout[3]);
      ast4(ap + 4,  vout[4],  vout[5],  vout[6],  vout[7]);
      ast4(ap + 8,  vout[8],  vout[9],  vout[10], vout[11]);
      ast4(ap + 12, vout[12], vout[13], vout[14], vout[15]);
    }
    gbar(cnt, (phase++)*NBLK);
    // ---------- P: attention + cell update (blocks 0..63, 2 rows each) ----------
    const float* arow = act + (size_t)(isP ? pb : 0)*NCOL;
    if (isP){
      float cw = ald(&arow[2816 + pd]);
      float s5[5];
      #pragma unroll
      for (int j = 0; j < 5; ++j){
        int k = phalf + 2*j;
        float li = ald(&arow[k*128 + pd]) * ald(&arow[1280 + k*128 + pd]);
        lL[(prow*10 + k)*128 + pd] = li;
        s5[j] = li * cw;
      }
      #pragma unroll
      for (int j = 0; j < 5; ++j){
        float s = s5[j];
        s += __shfl_down(s, 32); s += __shfl_down(s, 16); s += __shfl_down(s, 8);
        s += __shfl_down(s, 4);  s += __shfl_down(s, 2);  s += __shfl_down(s, 1);
        if ((tid & 63) == 0) part[tid >> 6][j] = s;
      }
    }
    __syncthreads();
    if (isP && tid < 20){
      int row = tid / 10, k = tid - row*10;
      int wbase = row*4 + (k & 1)*2;
      uL[row][k] = tanhf(part[wbase][k >> 1] + part[wbase + 1][k >> 1]);
    }
    __syncthreads();
    if (isP){
      float m = uL[prow][0];
      #pragma unroll
      for (int k = 1; k < 10; ++k) m = fmaxf(m, uL[prow][k]);
      float e[10]; float es = 0.f;
      #pragma unroll
      for (int k = 0; k < 10; ++k){ e[k] = expf(uL[prow][k] - m); es += e[k]; }
      float inv = 1.f / es;
      float sh = 0.f;
      if (phalf == 0){
        float lm = 0.f;
        #pragma unroll
        for (int k = 0; k < 10; ++k) lm = fmaf(e[k]*inv, lL[(prow*10 + k)*128 + pd], lm);
        float f = ald(&arow[2560 + pd]);
        float o = ald(&arow[2688 + pd]);
        float cn = fmaf(f, c_reg, lm);
        float hn = o * tanhf(cn);
        c_reg = cn;
        ast(&hR[pb*HH + pd], hn);
        ast(&cR[pb*HH + pd], cn);
        sh = fmaxf(hn, 0.f) * hw;
      }
      float s = sh;
      s += __shfl_down(s, 32); s += __shfl_down(s, 16); s += __shfl_down(s, 8);
      s += __shfl_down(s, 4);  s += __shfl_down(s, 2);  s += __shfl_down(s, 1);
      if ((tid & 63) == 0) part[tid >> 6][6] = s;
    }
    __syncthreads();
    if (isP && tid < 2){
      float s = part[tid*4][6] + part[tid*4 + 1][6];
      out[t*BB + bk*2 + tid] = fmaxf(s + hb, 0.f);
    }
    gbar(cnt, (phase++)*NBLK);
  }
}

extern "C" void kernel_launch(void* const* d_in, const int* in_sizes, int n_in,
                              void* d_out, int out_size, void* d_ws, size_t ws_size,
                              hipStream_t stream) {
  const float* feat  = (const float*)d_in[0];
  const float* Wih   = (const float*)d_in[1];
  const float* Whh   = (const float*)d_in[2];
  const float* bih   = (const float*)d_in[3];
  const float* bhh   = (const float*)d_in[4];
  const float* miWi  = (const float*)d_in[5];
  const float* miUi  = (const float*)d_in[6];
  const float* mibi  = (const float*)d_in[7];
  const float* miWc  = (const float*)d_in[8];
  const float* miUc  = (const float*)d_in[9];
  const float* mibc  = (const float*)d_in[10];
  const float* miWf  = (const float*)d_in[11];
  const float* miUf  = (const float*)d_in[12];
  const float* mibf  = (const float*)d_in[13];
  const float* miWo  = (const float*)d_in[14];
  const float* miUo  = (const float*)d_in[15];
  const float* mibo  = (const float*)d_in[16];
  const float* miWa  = (const float*)d_in[17];
  const float* headW = (const float*)d_in[18];
  const float* headb = (const float*)d_in[19];
  float* out = (float*)d_out;

  float* ws    = (float*)d_ws;
  float* w2t   = ws + OFF_W2T;
  float* bias2 = ws + OFF_BIAS2;
  float* ubig  = ws + OFF_UBIG;
  float* tilde = ws + OFF_TILDE;
  float* xi    = ws + OFF_XI;
  float* xc    = ws + OFF_XC;
  float* xf    = ws + OFF_XF;
  float* xo    = ws + OFF_XO;
  float* hR    = ws + OFF_HT;
  float* cR    = ws + OFF_CT;
  float* act   = ws + OFF_ACT;
  int*   cnt   = (int*)(ws + OFF_CNT);

  prep_w2t<<<dim3(SZ_W2T/256), dim3(256), 0, stream>>>(Wih, Whh, bih, bhh, w2t, bias2);
  prep_ubig<<<dim3((SZ_UBIG+255)/256), dim3(256), 0, stream>>>(miUi, miUc, miUf, miUo, miWa, ubig);
  zero_cnt<<<dim3(1), dim3(64), 0, stream>>>(cnt);
  lstm_scan<<<dim3(160), dim3(512), 0, stream>>>(feat, w2t, bias2, tilde);
  proj_ic<<<dim3(256, SS, 2), dim3(256), 0, stream>>>(tilde, miWi, mibi, miWc, mibc, xi, xc);
  proj_fo<<<dim3(256, 2), dim3(256), 0, stream>>>(tilde, miWf, mibf, miWo, mibo, xf, xo);

  void* kargs[] = { (void*)&ubig, (void*)&xi, (void*)&xc, (void*)&xf, (void*)&xo,
                    (void*)&headW, (void*)&headb, (void*)&hR, (void*)&cR,
                    (void*)&act, (void*)&cnt, (void*)&out };
  hipLaunchCooperativeKernel((const void*)mi_coop, dim3(NBLK), dim3(512), kargs, 0, stream);
}

// Round 9
// 8819.896 us; speedup vs baseline: 1.3201x; 1.0124x over previous
//
#include <hip/hip_runtime.h>
#include <math.h>

// Model: 10 parallel LSTMs -> MI-LSTM w/ stream attention -> linear head.
// All f32 (no fp32-input MFMA on CDNA4; accuracy threshold requires f32).
//
#define SS 10
#define TT 256
#define BB 128
#define HH 128
#define II 128
#define G4 512     // 4H
#define ZK 256     // I + H (fused [x|h] contraction)
#define NCOL 2944  // phase-D fused weight columns: Ui(1280)|Uc(1280)|Uf(128)|Uo(128)|Wa(128)
#define NBLK 92    // cooperative blocks: 92 x 32 cols = 2944

#define SZ_W2T   (SS*ZK*G4)        // 1,310,720
#define SZ_BIAS2 (SS*G4)           // 5,120
#define SZ_UBIG  (HH*NCOL)         // 376,832
#define SZ_TILDE (SS*TT*BB*HH)     // 41,943,040
#define SZ_X     (TT*SS*BB*HH)     // 41,943,040
#define SZ_XFO   (TT*BB*HH)        // 4,194,304

#define OFF_W2T   0
#define OFF_BIAS2 (OFF_W2T + SZ_W2T)
#define OFF_UBIG  (OFF_BIAS2 + SZ_BIAS2)
#define OFF_TILDE (OFF_UBIG + SZ_UBIG)
#define OFF_XI    (OFF_TILDE + SZ_TILDE)
#define OFF_XC    (OFF_XI + SZ_X)
#define OFF_XF    (OFF_XC + SZ_X)
#define OFF_XO    (OFF_XF + SZ_XFO)
#define OFF_HT    (OFF_XO + SZ_XFO)
#define OFF_CT    (OFF_HT + BB*HH)
#define OFF_ACT   (OFF_CT + BB*HH)
#define OFF_CNT   (OFF_ACT + BB*NCOL)

__device__ __forceinline__ float sigf(float x){ return 1.0f/(1.0f+expf(-x)); }

// per-access coherent ops (sc0/sc1 path; no cache-wide wb/inv)
__device__ __forceinline__ float ald(const float* p){
  return __hip_atomic_load(p, __ATOMIC_RELAXED, __HIP_MEMORY_SCOPE_AGENT);
}
__device__ __forceinline__ void ast(float* p, float v){
  __hip_atomic_store(p, v, __ATOMIC_RELAXED, __HIP_MEMORY_SCOPE_AGENT);
}
__device__ __forceinline__ int aldi(const int* p){
  return __hip_atomic_load(p, __ATOMIC_RELAXED, __HIP_MEMORY_SCOPE_AGENT);
}
__device__ __forceinline__ void asti(int* p, int v){
  __hip_atomic_store(p, v, __ATOMIC_RELAXED, __HIP_MEMORY_SCOPE_AGENT);
}
// 16B coherent ops. ext_vector_type binds to a VGPR quad (HIP float4 is a struct, cannot).
typedef float f32x4v __attribute__((ext_vector_type(4)));
__device__ __forceinline__ void ast4(float* p, float a, float b, float c, float d){
  f32x4v w; w.x = a; w.y = b; w.z = c; w.w = d;
  asm volatile("global_store_dwordx4 %0, %1, off sc0 sc1" :: "v"(p), "v"(w) : "memory");
}
__device__ __forceinline__ f32x4v ald4(const float* p){
  f32x4v r;
  asm volatile("global_load_dwordx4 %0, %1, off sc0 sc1" : "=v"(r) : "v"(p) : "memory");
  return r;
}

// ---------------- prep: fused transposed LSTM weights (b128-friendly) ----------------
__global__ __launch_bounds__(256) void prep_w2t(const float* __restrict__ Wih, const float* __restrict__ Whh,
                                                const float* __restrict__ bih, const float* __restrict__ bhh,
                                                float* __restrict__ w2t, float* __restrict__ bias2){
  int idx = blockIdx.x*256 + threadIdx.x;
  if (idx < SZ_W2T){
    int q = idx & 3; int j = (idx >> 2) & 511; int kk4 = (idx >> 11) & 63; int s = idx >> 17;
    int kk = kk4*4 + q;
    float v = (kk < II) ? Wih[(s*G4 + j)*II + kk] : Whh[(s*G4 + j)*HH + (kk - II)];
    w2t[idx] = v;
  }
  if (idx < SZ_BIAS2) bias2[idx] = bih[idx] + bhh[idx];
}

__global__ __launch_bounds__(256) void prep_ubig(const float* __restrict__ Ui, const float* __restrict__ Uc,
                                                 const float* __restrict__ Uf, const float* __restrict__ Uo,
                                                 const float* __restrict__ Wa, float* __restrict__ ubig){
  int idx = blockIdx.x*256 + threadIdx.x;
  if (idx >= SZ_UBIG) return;
  int col = idx % NCOL; int h = idx / NCOL;
  float v;
  if (col < 1280){ int k = col >> 7, d = col & 127; v = Ui[(k*HH + h)*HH + d]; }
  else if (col < 2560){ int c2 = col - 1280; int k = c2 >> 7, d = c2 & 127; v = Uc[(k*HH + h)*HH + d]; }
  else if (col < 2688){ v = Uf[h*HH + (col - 2560)]; }
  else if (col < 2816){ v = Uo[h*HH + (col - 2688)]; }
  else               { v = Wa[h*HH + (col - 2816)]; }
  ubig[idx] = v;
}

// ---------------- phase B: fused 10x LSTM scan (4 rows/block, 320 blocks) ----------------
__global__ __launch_bounds__(512) void lstm_scan(const float* __restrict__ feat, const float* __restrict__ w2t,
                                                 const float* __restrict__ bias2, float* __restrict__ tilde){
  int p = blockIdx.x;                 // 0..319
  int g = (p & 7) * 40 + (p >> 3);    // XCD-contiguous logical id
  int s = g >> 5; int rb = g & 31; int b0 = rb * 4;
  int tid = threadIdx.x;
  __shared__ float z[4][ZK];
  __shared__ float gl[4][G4];
  const float* w2ts = w2t + (size_t)s*ZK*G4;
  float bj = bias2[s*G4 + tid];
  float c0 = 0.f, c1 = 0.f;
  if (tid < 256){
    int r = tid >> 6; int k = (tid*2) & 127;
    z[r][128+k] = 0.f; z[r][128+k+1] = 0.f;
    const float* xrow = feat + ((s*TT + 0)*BB + (b0+r))*II;
    float2 xv = *(const float2*)(xrow + k);
    z[r][k] = xv.x; z[r][k+1] = xv.y;
  }
  __syncthreads();
  for (int t = 0; t < TT; ++t){
    float acc[4];
    #pragma unroll
    for (int r=0;r<4;++r) acc[r] = bj;
    for (int kk4 = 0; kk4 < 64; ++kk4){
      float4 wv = *(const float4*)&w2ts[(kk4*G4 + tid)*4];
      #pragma unroll
      for (int r=0;r<4;++r){
        float4 zv = *(const float4*)&z[r][kk4*4];
        acc[r] = fmaf(zv.w, wv.w, fmaf(zv.z, wv.z, fmaf(zv.y, wv.y, fmaf(zv.x, wv.x, acc[r]))));
      }
    }
    int gtype = tid >> 7;
    #pragma unroll
    for (int r=0;r<4;++r){
      float v = acc[r];
      v = (gtype == 2) ? tanhf(v) : sigf(v);
      gl[r][tid] = v;
    }
    __syncthreads();
    if (tid < 256){
      int r = tid >> 6; int k = (tid*2) & 127;
      float si0 = gl[r][k],     si1 = gl[r][k+1];
      float sf0 = gl[r][128+k], sf1 = gl[r][128+k+1];
      float tg0 = gl[r][256+k], tg1 = gl[r][256+k+1];
      float so0 = gl[r][384+k], so1 = gl[r][384+k+1];
      c0 = sf0*c0 + si0*tg0;
      c1 = sf1*c1 + si1*tg1;
      float h0 = so0*tanhf(c0), h1 = so1*tanhf(c1);
      z[r][128+k] = h0; z[r][128+k+1] = h1;
      float2 tv = make_float2(fmaxf(h0,0.f), fmaxf(h1,0.f));
      *(float2*)&tilde[((s*TT + t)*BB + (b0+r))*HH + k] = tv;
      if (t+1 < TT){
        const float* xrow = feat + ((s*TT + (t+1))*BB + (b0+r))*II;
        float2 xv = *(const float2*)(xrow + k);
        z[r][k] = xv.x; z[r][k+1] = xv.y;
      }
    }
    __syncthreads();
  }
}

// ---------------- phase C: projections (unchanged) ----------------
__global__ __launch_bounds__(256) void proj_ic(const float* __restrict__ tilde,
                                               const float* __restrict__ Wi, const float* __restrict__ bi,
                                               const float* __restrict__ Wc, const float* __restrict__ bc,
                                               float* __restrict__ xi, float* __restrict__ xc){
  const int k = blockIdx.y;
  const int isc = blockIdx.z;
  const float* W = (isc ? Wc : Wi) + k*HH*HH;
  const float* bias = (isc ? bc : bi) + k*HH;
  float* out = isc ? xc : xi;
  const int m0 = blockIdx.x * 128;
  const int tid = threadIdx.x;
  __shared__ float Wl[HH*HH];
  __shared__ float Al[32*HH];
  for (int u = 0; u < 64; ++u) Wl[u*256 + tid] = W[u*256 + tid];
  const int tx = tid & 31, ty = tid >> 5;
  const int d0 = tx*4;
  float4 bv = *(const float4*)&bias[d0];
  __syncthreads();
  for (int ch = 0; ch < 4; ++ch){
    const float* Arow = tilde + (size_t)(k*TT*BB + m0 + ch*32)*HH;
    #pragma unroll
    for (int u = 0; u < 4; ++u)
      *(float4*)&Al[u*1024 + tid*4] = *(const float4*)&Arow[u*1024 + tid*4];
    __syncthreads();
    float4 a0 = bv, a1 = bv, a2 = bv, a3 = bv;
    for (int h = 0; h < HH; ++h){
      float4 w4 = *(const float4*)&Wl[h*HH + d0];
      float A0 = Al[(ty   )*HH + h], A1 = Al[(ty+ 8)*HH + h];
      float A2 = Al[(ty+16)*HH + h], A3 = Al[(ty+24)*HH + h];
      a0.x = fmaf(A0,w4.x,a0.x); a0.y = fmaf(A0,w4.y,a0.y); a0.z = fmaf(A0,w4.z,a0.z); a0.w = fmaf(A0,w4.w,a0.w);
      a1.x = fmaf(A1,w4.x,a1.x); a1.y = fmaf(A1,w4.y,a1.y); a1.z = fmaf(A1,w4.z,a1.z); a1.w = fmaf(A1,w4.w,a1.w);
      a2.x = fmaf(A2,w4.x,a2.x); a2.y = fmaf(A2,w4.y,a2.y); a2.z = fmaf(A2,w4.z,a2.z); a2.w = fmaf(A2,w4.w,a2.w);
      a3.x = fmaf(A3,w4.x,a3.x); a3.y = fmaf(A3,w4.y,a3.y); a3.z = fmaf(A3,w4.z,a3.z); a3.w = fmaf(A3,w4.w,a3.w);
    }
    float4 accs[4] = {a0,a1,a2,a3};
    #pragma unroll
    for (int i = 0; i < 4; ++i){
      int m = m0 + ch*32 + ty + 8*i;
      int t = m >> 7, b = m & 127;
      *(float4*)&out[((t*SS + k)*BB + b)*HH + d0] = accs[i];
    }
    __syncthreads();
  }
}

__global__ __launch_bounds__(256) void proj_fo(const float* __restrict__ tilde,
                                               const float* __restrict__ Wf, const float* __restrict__ bf,
                                               const float* __restrict__ Wo, const float* __restrict__ bo,
                                               float* __restrict__ xf, float* __restrict__ xo){
  const int iso = blockIdx.y;
  const float* W = iso ? Wo : Wf;
  const float* bias = iso ? bo : bf;
  float* out = iso ? xo : xf;
  const int m0 = blockIdx.x * 128;
  const int tid = threadIdx.x;
  __shared__ float Wl[HH*HH];
  __shared__ float Al[32*HH];
  for (int u = 0; u < 64; ++u) Wl[u*256 + tid] = W[u*256 + tid];
  const int tx = tid & 31, ty = tid >> 5;
  const int d0 = tx*4;
  float4 bv = *(const float4*)&bias[d0];
  __syncthreads();
  for (int ch = 0; ch < 4; ++ch){
    const float* Arow = tilde + (size_t)(m0 + ch*32)*HH;
    #pragma unroll
    for (int u = 0; u < 4; ++u)
      *(float4*)&Al[u*1024 + tid*4] = *(const float4*)&Arow[u*1024 + tid*4];
    __syncthreads();
    float4 a0 = bv, a1 = bv, a2 = bv, a3 = bv;
    for (int h = 0; h < HH; ++h){
      float4 w4 = *(const float4*)&Wl[h*HH + d0];
      float A0 = Al[(ty   )*HH + h], A1 = Al[(ty+ 8)*HH + h];
      float A2 = Al[(ty+16)*HH + h], A3 = Al[(ty+24)*HH + h];
      a0.x = fmaf(A0,w4.x,a0.x); a0.y = fmaf(A0,w4.y,a0.y); a0.z = fmaf(A0,w4.z,a0.z); a0.w = fmaf(A0,w4.w,a0.w);
      a1.x = fmaf(A1,w4.x,a1.x); a1.y = fmaf(A1,w4.y,a1.y); a1.z = fmaf(A1,w4.z,a1.z); a1.w = fmaf(A1,w4.w,a1.w);
      a2.x = fmaf(A2,w4.x,a2.x); a2.y = fmaf(A2,w4.y,a2.y); a2.z = fmaf(A2,w4.z,a2.z); a2.w = fmaf(A2,w4.w,a2.w);
      a3.x = fmaf(A3,w4.x,a3.x); a3.y = fmaf(A3,w4.y,a3.y); a3.z = fmaf(A3,w4.z,a3.z); a3.w = fmaf(A3,w4.w,a3.w);
    }
    float4 accs[4] = {a0,a1,a2,a3};
    #pragma unroll
    for (int i = 0; i < 4; ++i){
      int m = m0 + ch*32 + ty + 8*i;
      *(float4*)&out[(size_t)m*HH + d0] = accs[i];
    }
    __syncthreads();
  }
}

// ---------------- phase D: cooperative weight-stationary MI-LSTM scan ----------------
// Flag-array barrier: each block WRITES its own slot (parallel, no RMW serialization);
// threads 0..91 poll one flag each. vmcnt(0) drains sc1 stores before arrival.
__device__ __forceinline__ void gbar(int* flags, int bk, int p){
  asm volatile("s_waitcnt vmcnt(0)" ::: "memory");
  __syncthreads();
  if (threadIdx.x == 0) asti(&flags[bk], p);
  if (threadIdx.x < NBLK){
    while (aldi(&flags[threadIdx.x]) < p) __builtin_amdgcn_s_sleep(2);
  }
  __syncthreads();
}

__global__ void zero_cnt(int* cnt){ if (threadIdx.x < 128) cnt[threadIdx.x] = 0; }

// 92 blocks x 512 threads. Block bk owns 32 Ubig columns (16KB LDS, persistent).
// hR/cR ROW-major [b][d]. Per step: [stage hR->hL via dwordx4 sc1, XOR-swizzled] ->
// [4x4 GEMM, rows rq+32i (pan writes conflict-free)] -> [panel + x + act full-line
// stores] -> flagbar -> P (blocks 0..63, 2 rows each) -> flagbar.
__global__ __launch_bounds__(512) void mi_coop(
    const float* __restrict__ ubig,
    const float* __restrict__ xi, const float* __restrict__ xc,
    const float* __restrict__ xf, const float* __restrict__ xo,
    const float* __restrict__ headW, const float* __restrict__ headb,
    float* hR, float* cR,
    float* act, int* flags, float* __restrict__ out)
{
  const int bk = blockIdx.x;
  const int tid = threadIdx.x;
  __shared__ float Wl[128*32];                 // 16KB weights, persistent
  __shared__ __align__(16) float hL[128*128];  // 64KB state stage, [b][d^swz]
  __shared__ float pan[128*33];                // raw-gate panel
  __shared__ float lL[20*128];
  __shared__ float part[8][8];
  __shared__ float uL[2][10];
  const int col = tid & 31, rg5 = tid >> 5;
  const int gcol = bk*32 + col;
  for (int h = rg5; h < 128; h += 16) Wl[h*32 + col] = ubig[(size_t)h*NCOL + gcol];

  int btype;
  if (bk < 40) btype = 0; else if (bk < 80) btype = 1;
  else if (bk < 84) btype = 2; else if (bk < 88) btype = 3; else btype = 4;

  // GEMM tile: rows {rq, rq+32, rq+64, rq+96}, block-local cols c0..c0+3
  const int cq = tid >> 5;        // 0..7 (tid<256)
  const int rq = tid & 31;
  const int c0 = cq*4;
  const int kk = ((rq >> 2) & 7) << 2;   // swizzle key, invariant across the 4 rows

  // panel-reader / x / act-store role: 1 row x 16 cols (= one 64B line)
  const int prd_row = tid >> 1, prd_co = (tid & 1) * 16;
  const float* xrd = nullptr; size_t xrd_step = 0;
  if (tid < 256 && btype != 4){
    if (btype == 0){ int k = bk >> 2; int dloc = (bk & 3)*32 + prd_co;
      xrd = xi + ((size_t)k*BB + prd_row)*HH + dloc; xrd_step = (size_t)SS*BB*HH; }
    else if (btype == 1){ int k = (bk-40) >> 2; int dloc = ((bk-40) & 3)*32 + prd_co;
      xrd = xc + ((size_t)k*BB + prd_row)*HH + dloc; xrd_step = (size_t)SS*BB*HH; }
    else if (btype == 2){ int dloc = (bk-80)*32 + prd_co;
      xrd = xf + (size_t)prd_row*HH + dloc; xrd_step = (size_t)BB*HH; }
    else { int dloc = (bk-84)*32 + prd_co;
      xrd = xo + (size_t)prd_row*HH + dloc; xrd_step = (size_t)BB*HH; }
  }

  const int prow = tid >> 8, pd = tid & 127, phalf = (tid >> 7) & 1;
  const int pb = bk*2 + prow;
  const bool isP = (bk < 64);
  float c_reg = 0.f;
  float hw = headW[pd];
  float hb = headb[0];
  if (isP && phalf == 0){ ast(&hR[pb*HH + pd], 0.f); ast(&cR[pb*HH + pd], 0.f); }

  int ph = 1;
  gbar(flags, bk, ph++);

  for (int t = 0; t < TT; ++t){
    // ---------- x prefetch (reader-pattern: 16 consecutive cols of one row) ----------
    float4 xv[4];
    if (tid < 256 && btype != 4){
      const float* xp = xrd + (size_t)t*xrd_step;
      xv[0] = *(const float4*)(xp);      xv[1] = *(const float4*)(xp + 4);
      xv[2] = *(const float4*)(xp + 8);  xv[3] = *(const float4*)(xp + 12);
    } else {
      xv[0] = xv[1] = xv[2] = xv[3] = make_float4(0.f,0.f,0.f,0.f);
    }
    // ---------- stage state (dwordx4 sc1 loads, swizzled LDS writes) ----------
    const float* src = (btype == 4) ? cR : hR;
    f32x4v sv[8];
    #pragma unroll
    for (int u = 0; u < 8; ++u) sv[u] = ald4(&src[(u*512 + tid)*4]);
    asm volatile("s_waitcnt vmcnt(0)" ::: "memory");
    #pragma unroll
    for (int u = 0; u < 8; ++u){
      int lin = u*512 + tid;         // float4 index, 4096 total
      int b = lin >> 5;
      int d0 = (lin & 31) * 4;
      int key = ((b >> 2) & 7) << 2;
      *(f32x4v*)&hL[b*128 + (d0 ^ key)] = sv[u];
    }
    __syncthreads();
    // ---------- G: 4x4 register-tiled GEMM (rows rq+32i) ----------
    if (tid < 256){
      float acc[4][4] = {{0.f,0.f,0.f,0.f},{0.f,0.f,0.f,0.f},{0.f,0.f,0.f,0.f},{0.f,0.f,0.f,0.f}};
      for (int d0 = 0; d0 < 128; d0 += 4){
        int dsw = d0 ^ kk;
        float4 av0 = *(const float4*)&hL[(rq     )*128 + dsw];
        float4 av1 = *(const float4*)&hL[(rq + 32)*128 + dsw];
        float4 av2 = *(const float4*)&hL[(rq + 64)*128 + dsw];
        float4 av3 = *(const float4*)&hL[(rq + 96)*128 + dsw];
        float4 wv0 = *(const float4*)&Wl[(d0+0)*32 + c0];
        float4 wv1 = *(const float4*)&Wl[(d0+1)*32 + c0];
        float4 wv2 = *(const float4*)&Wl[(d0+2)*32 + c0];
        float4 wv3 = *(const float4*)&Wl[(d0+3)*32 + c0];
        float4 avs[4] = {av0, av1, av2, av3};
        float4 wvs[4] = {wv0, wv1, wv2, wv3};
        #pragma unroll
        for (int i = 0; i < 4; ++i){
          float a0 = avs[i].x, a1 = avs[i].y, a2 = avs[i].z, a3 = avs[i].w;
          acc[i][0] = fmaf(a0, wvs[0].x, acc[i][0]); acc[i][1] = fmaf(a0, wvs[0].y, acc[i][1]);
          acc[i][2] = fmaf(a0, wvs[0].z, acc[i][2]); acc[i][3] = fmaf(a0, wvs[0].w, acc[i][3]);
          acc[i][0] = fmaf(a1, wvs[1].x, acc[i][0]); acc[i][1] = fmaf(a1, wvs[1].y, acc[i][1]);
          acc[i][2] = fmaf(a1, wvs[1].z, acc[i][2]); acc[i][3] = fmaf(a1, wvs[1].w, acc[i][3]);
          acc[i][0] = fmaf(a2, wvs[2].x, acc[i][0]); acc[i][1] = fmaf(a2, wvs[2].y, acc[i][1]);
          acc[i][2] = fmaf(a2, wvs[2].z, acc[i][2]); acc[i][3] = fmaf(a2, wvs[2].w, acc[i][3]);
          acc[i][0] = fmaf(a3, wvs[3].x, acc[i][0]); acc[i][1] = fmaf(a3, wvs[3].y, acc[i][1]);
          acc[i][2] = fmaf(a3, wvs[3].z, acc[i][2]); acc[i][3] = fmaf(a3, wvs[3].w, acc[i][3]);
        }
      }
      // raw gates -> panel; bank = (rq + c0 + j) mod 32 -> conflict-free
      #pragma unroll
      for (int i = 0; i < 4; ++i)
        #pragma unroll
        for (int j = 0; j < 4; ++j)
          pan[(rq + 32*i)*33 + c0 + j] = acc[i][j];
    }
    __syncthreads();
    // ---------- panel read + x add + activation + full-line act store ----------
    if (tid < 256){
      float vout[16];
      #pragma unroll
      for (int u = 0; u < 16; ++u){
        float pv = pan[prd_row*33 + prd_co + u] + ((&xv[0].x)[u]);
        float v;
        if (btype == 1) v = tanhf(pv);
        else if (btype == 4) v = pv;
        else v = sigf(pv);
        vout[u] = v;
      }
      float* ap = &act[(size_t)prd_row*NCOL + (size_t)bk*32 + prd_co];
      ast4(ap,      vout[0],  vout[1],  vout[2],  vout[3]);
      ast4(ap + 4,  vout[4],  vout[5],  vout[6],  vout[7]);
      ast4(ap + 8,  vout[8],  vout[9],  vout[10], vout[11]);
      ast4(ap + 12, vout[12], vout[13], vout[14], vout[15]);
    }
    gbar(flags, bk, ph++);
    // ---------- P: attention + cell update (blocks 0..63, 2 rows each) ----------
    const float* arow = act + (size_t)(isP ? pb : 0)*NCOL;
    if (isP){
      float cw = ald(&arow[2816 + pd]);
      float s5[5];
      #pragma unroll
      for (int j = 0; j < 5; ++j){
        int k = phalf + 2*j;
        float li = ald(&arow[k*128 + pd]) * ald(&arow[1280 + k*128 + pd]);
        lL[(prow*10 + k)*128 + pd] = li;
        s5[j] = li * cw;
      }
      #pragma unroll
      for (int j = 0; j < 5; ++j){
        float s = s5[j];
        s += __shfl_down(s, 32); s += __shfl_down(s, 16); s += __shfl_down(s, 8);
        s += __shfl_down(s, 4);  s += __shfl_down(s, 2);  s += __shfl_down(s, 1);
        if ((tid & 63) == 0) part[tid >> 6][j] = s;
      }
    }
    __syncthreads();
    if (isP && tid < 20){
      int row = tid / 10, k = tid - row*10;
      int wbase = row*4 + (k & 1)*2;
      uL[row][k] = tanhf(part[wbase][k >> 1] + part[wbase + 1][k >> 1]);
    }
    __syncthreads();
    if (isP){
      float m = uL[prow][0];
      #pragma unroll
      for (int k = 1; k < 10; ++k) m = fmaxf(m, uL[prow][k]);
      float e[10]; float es = 0.f;
      #pragma unroll
      for (int k = 0; k < 10; ++k){ e[k] = expf(uL[prow][k] - m); es += e[k]; }
      float inv = 1.f / es;
      float sh = 0.f;
      if (phalf == 0){
        float lm = 0.f;
        #pragma unroll
        for (int k = 0; k < 10; ++k) lm = fmaf(e[k]*inv, lL[(prow*10 + k)*128 + pd], lm);
        float f = ald(&arow[2560 + pd]);
        float o = ald(&arow[2688 + pd]);
        float cn = fmaf(f, c_reg, lm);
        float hn = o * tanhf(cn);
        c_reg = cn;
        ast(&hR[pb*HH + pd], hn);
        ast(&cR[pb*HH + pd], cn);
        sh = fmaxf(hn, 0.f) * hw;
      }
      float s = sh;
      s += __shfl_down(s, 32); s += __shfl_down(s, 16); s += __shfl_down(s, 8);
      s += __shfl_down(s, 4);  s += __shfl_down(s, 2);  s += __shfl_down(s, 1);
      if ((tid & 63) == 0) part[tid >> 6][6] = s;
    }
    __syncthreads();
    if (isP && tid < 2){
      float s = part[tid*4][6] + part[tid*4 + 1][6];
      out[t*BB + bk*2 + tid] = fmaxf(s + hb, 0.f);
    }
    gbar(flags, bk, ph++);
  }
}

extern "C" void kernel_launch(void* const* d_in, const int* in_sizes, int n_in,
                              void* d_out, int out_size, void* d_ws, size_t ws_size,
                              hipStream_t stream) {
  const float* feat  = (const float*)d_in[0];
  const float* Wih   = (const float*)d_in[1];
  const float* Whh   = (const float*)d_in[2];
  const float* bih   = (const float*)d_in[3];
  const float* bhh   = (const float*)d_in[4];
  const float* miWi  = (const float*)d_in[5];
  const float* miUi  = (const float*)d_in[6];
  const float* mibi  = (const float*)d_in[7];
  const float* miWc  = (const float*)d_in[8];
  const float* miUc  = (const float*)d_in[9];
  const float* mibc  = (const float*)d_in[10];
  const float* miWf  = (const float*)d_in[11];
  const float* miUf  = (const float*)d_in[12];
  const float* mibf  = (const float*)d_in[13];
  const float* miWo  = (const float*)d_in[14];
  const float* miUo  = (const float*)d_in[15];
  const float* mibo  = (const float*)d_in[16];
  const float* miWa  = (const float*)d_in[17];
  const float* headW = (const float*)d_in[18];
  const float* headb = (const float*)d_in[19];
  float* out = (float*)d_out;

  float* ws    = (float*)d_ws;
  float* w2t   = ws + OFF_W2T;
  float* bias2 = ws + OFF_BIAS2;
  float* ubig  = ws + OFF_UBIG;
  float* tilde = ws + OFF_TILDE;
  float* xi    = ws + OFF_XI;
  float* xc    = ws + OFF_XC;
  float* xf    = ws + OFF_XF;
  float* xo    = ws + OFF_XO;
  float* hR    = ws + OFF_HT;
  float* cR    = ws + OFF_CT;
  float* act   = ws + OFF_ACT;
  int*   flags = (int*)(ws + OFF_CNT);

  prep_w2t<<<dim3(SZ_W2T/256), dim3(256), 0, stream>>>(Wih, Whh, bih, bhh, w2t, bias2);
  prep_ubig<<<dim3((SZ_UBIG+255)/256), dim3(256), 0, stream>>>(miUi, miUc, miUf, miUo, miWa, ubig);
  zero_cnt<<<dim3(1), dim3(128), 0, stream>>>(flags);
  lstm_scan<<<dim3(320), dim3(512), 0, stream>>>(feat, w2t, bias2, tilde);
  proj_ic<<<dim3(256, SS, 2), dim3(256), 0, stream>>>(tilde, miWi, mibi, miWc, mibc, xi, xc);
  proj_fo<<<dim3(256, 2), dim3(256), 0, stream>>>(tilde, miWf, mibf, miWo, mibo, xf, xo);

  void* kargs[] = { (void*)&ubig, (void*)&xi, (void*)&xc, (void*)&xf, (void*)&xo,
                    (void*)&headW, (void*)&headb, (void*)&hR, (void*)&cR,
                    (void*)&act, (void*)&flags, (void*)&out };
  hipLaunchCooperativeKernel((const void*)mi_coop, dim3(NBLK), dim3(512), kargs, 0, stream);
}